// Round 1
// baseline (7216.976 us; speedup 1.0000x reference)
//
#include <hip/hip_runtime.h>
#include <hip/hip_bf16.h>

// Problem constants (from reference)
#define B_    16
#define N_    8192
#define NPOINT 2048
#define K_    16
#define CIN   64
#define COUT  128
#define BN_EPS 1e-5f

// ---------------------------------------------------------------------------
// 1) Farthest point sampling: one block (1024 threads) per batch.
//    Points live in registers (8 per thread). Bit-exact numpy arithmetic:
//    ((dx*dx + dy*dy) + dz*dz) with _rn intrinsics (no FMA contraction),
//    fminf accumulation, argmax with first-index tie-break.
// ---------------------------------------------------------------------------
__global__ __launch_bounds__(1024, 1) void fps_kernel(const float* __restrict__ xyz,
                                                      int* __restrict__ fps_idx) {
    const int b = blockIdx.x;
    const float* P = xyz + (size_t)b * N_ * 3;
    const int t = threadIdx.x;

    float px[8], py[8], pz[8], dist[8];
#pragma unroll
    for (int k = 0; k < 8; ++k) {
        int gi = t + (k << 10);
        px[k] = P[gi * 3 + 0];
        py[k] = P[gi * 3 + 1];
        pz[k] = P[gi * 3 + 2];
        dist[k] = 1e10f;
    }

    __shared__ float s_v[16];
    __shared__ int   s_i[16];
    __shared__ float s_c[3];
    __shared__ int   s_widx;

    if (t == 0) {
        fps_idx[b * NPOINT + 0] = 0;          // initial farthest = 0
        s_c[0] = px[0]; s_c[1] = py[0]; s_c[2] = pz[0];  // thread 0, k=0 owns point 0
    }
    __syncthreads();

    const int lane = t & 63;
    const int wave = t >> 6;

    for (int it = 1; it < NPOINT; ++it) {
        float cx = s_c[0], cy = s_c[1], cz = s_c[2];
        float bv = -1.0f; int bi = 0;
#pragma unroll
        for (int k = 0; k < 8; ++k) {
            float dx = __fsub_rn(px[k], cx);
            float dy = __fsub_rn(py[k], cy);
            float dz = __fsub_rn(pz[k], cz);
            float d  = __fadd_rn(__fadd_rn(__fmul_rn(dx, dx), __fmul_rn(dy, dy)),
                                 __fmul_rn(dz, dz));
            float nd = fminf(dist[k], d);
            dist[k] = nd;
            // ascending k => ascending global index; strict > keeps lowest idx on ties
            if (nd > bv) { bv = nd; bi = t + (k << 10); }
        }
        // wave (64-lane) argmax reduce, tie-break to smaller global index
#pragma unroll
        for (int off = 32; off >= 1; off >>= 1) {
            float ov = __shfl_down(bv, off, 64);
            int   oi = __shfl_down(bi, off, 64);
            if (ov > bv || (ov == bv && oi < bi)) { bv = ov; bi = oi; }
        }
        if (lane == 0) { s_v[wave] = bv; s_i[wave] = bi; }
        __syncthreads();
        if (t == 0) {
            float wv = s_v[0]; int wi = s_i[0];
#pragma unroll
            for (int w = 1; w < 16; ++w) {
                float ov = s_v[w]; int oi = s_i[w];
                if (ov > wv || (ov == wv && oi < wi)) { wv = ov; wi = oi; }
            }
            s_widx = wi;
            fps_idx[b * NPOINT + it] = wi;
        }
        __syncthreads();
        int widx = s_widx;
        if ((widx & 1023) == t) {            // owner thread broadcasts centroid coords
            int k = widx >> 10;
            float cx2 = px[0], cy2 = py[0], cz2 = pz[0];
#pragma unroll
            for (int kk = 1; kk < 8; ++kk) {
                if (k == kk) { cx2 = px[kk]; cy2 = py[kk]; cz2 = pz[kk]; }
            }
            s_c[0] = cx2; s_c[1] = cy2; s_c[2] = cz2;
        }
        __syncthreads();
    }
}

// ---------------------------------------------------------------------------
// 2) new_xyz gather: out[b][q][c] = xyz[b][fps_idx[b][q]][c]
// ---------------------------------------------------------------------------
__global__ void newxyz_kernel(const float* __restrict__ xyz,
                              const int* __restrict__ fps_idx,
                              float* __restrict__ out) {
    int i = blockIdx.x * blockDim.x + threadIdx.x;
    if (i >= B_ * NPOINT * 3) return;
    int c = i % 3;
    int q = (i / 3) % NPOINT;
    int b = i / (3 * NPOINT);
    out[i] = xyz[((size_t)b * N_ + fps_idx[b * NPOINT + q]) * 3 + c];
}

// ---------------------------------------------------------------------------
// 3) kNN: thread per query, xyz tiled through LDS (broadcast reads),
//    16-deep sorted register list, strict < (stable / first-index ties).
// ---------------------------------------------------------------------------
#define KNN_TILE 1024
__global__ __launch_bounds__(256) void knn_kernel(const float* __restrict__ xyz,
                                                  const int* __restrict__ fps_idx,
                                                  int* __restrict__ knn_idx) {
    const int b = blockIdx.y;
    const int q = blockIdx.x * 256 + threadIdx.x;   // 0..2047
    const float* P = xyz + (size_t)b * N_ * 3;
    const int qi = fps_idx[b * NPOINT + q];
    const float qx = P[qi * 3 + 0], qy = P[qi * 3 + 1], qz = P[qi * 3 + 2];

    float bd[K_]; int bix[K_];
#pragma unroll
    for (int j = 0; j < K_; ++j) { bd[j] = 3.4e38f; bix[j] = 0; }

    __shared__ float sx[KNN_TILE], sy[KNN_TILE], sz[KNN_TILE];

    for (int tile = 0; tile < N_; tile += KNN_TILE) {
        for (int i = threadIdx.x; i < KNN_TILE; i += 256) {
            sx[i] = P[(tile + i) * 3 + 0];
            sy[i] = P[(tile + i) * 3 + 1];
            sz[i] = P[(tile + i) * 3 + 2];
        }
        __syncthreads();
        for (int i = 0; i < KNN_TILE; ++i) {
            float dx = __fsub_rn(qx, sx[i]);
            float dy = __fsub_rn(qy, sy[i]);
            float dz = __fsub_rn(qz, sz[i]);
            float d  = __fadd_rn(__fadd_rn(__fmul_rn(dx, dx), __fmul_rn(dy, dy)),
                                 __fmul_rn(dz, dz));
            if (d < bd[K_ - 1]) {              // strict: equal distances keep earlier idx
                bd[K_ - 1] = d; bix[K_ - 1] = tile + i;
#pragma unroll
                for (int j = K_ - 1; j > 0; --j) {
                    if (bd[j] < bd[j - 1]) {
                        float tv = bd[j]; bd[j] = bd[j - 1]; bd[j - 1] = tv;
                        int   ti = bix[j]; bix[j] = bix[j - 1]; bix[j - 1] = ti;
                    }
                }
            }
        }
        __syncthreads();
    }
#pragma unroll
    for (int j = 0; j < K_; ++j)
        knn_idx[((size_t)b * NPOINT + q) * K_ + j] = bix[j];
}

// ---------------------------------------------------------------------------
// 4) 1x1 conv GEMM: h[131072,128] = feat[131072,64] @ W^T + b, fp32 vector.
//    Block = 64 rows x 128 cols tile. Also emits per-block channel sum/sumsq.
// ---------------------------------------------------------------------------
__global__ __launch_bounds__(256) void gemm_kernel(const float* __restrict__ feat,
                                                   const float* __restrict__ W,
                                                   const float* __restrict__ bias,
                                                   float* __restrict__ h,
                                                   float* __restrict__ partials) {
    __shared__ float wT[64 * 132];      // wT[c*132 + o], pad to keep 16B align + spread banks
    __shared__ float fT[64 * 68];       // fT[c*68 + r]
    __shared__ float redsum[COUT], redsq[COUT];
    const int tid = threadIdx.x;
    const size_t row0 = (size_t)blockIdx.x * 64;

    for (int g = tid; g < COUT * CIN; g += 256) {
        int o = g >> 6, c = g & 63;
        wT[c * 132 + o] = W[g];
    }
    for (int g = tid; g < 64 * CIN; g += 256) {
        int r = g >> 6, c = g & 63;
        fT[c * 68 + r] = feat[(row0 + r) * CIN + c];
    }
    if (tid < COUT) { redsum[tid] = 0.f; redsq[tid] = 0.f; }
    __syncthreads();

    const int rbase = (tid >> 4) * 4;   // 0..60
    const int cbase = (tid & 15) * 8;   // 0..120  (consecutive lanes -> consecutive cols)

    float acc[4][8];
#pragma unroll
    for (int r = 0; r < 4; ++r)
#pragma unroll
        for (int j = 0; j < 8; ++j) acc[r][j] = bias[cbase + j];

    for (int c = 0; c < CIN; ++c) {
        float f0 = fT[c * 68 + rbase + 0];
        float f1 = fT[c * 68 + rbase + 1];
        float f2 = fT[c * 68 + rbase + 2];
        float f3 = fT[c * 68 + rbase + 3];
        float wv[8];
#pragma unroll
        for (int j = 0; j < 8; ++j) wv[j] = wT[c * 132 + cbase + j];
#pragma unroll
        for (int j = 0; j < 8; ++j) {
            acc[0][j] = fmaf(f0, wv[j], acc[0][j]);
            acc[1][j] = fmaf(f1, wv[j], acc[1][j]);
            acc[2][j] = fmaf(f2, wv[j], acc[2][j]);
            acc[3][j] = fmaf(f3, wv[j], acc[3][j]);
        }
    }

    float psum[8], psq[8];
#pragma unroll
    for (int j = 0; j < 8; ++j) { psum[j] = 0.f; psq[j] = 0.f; }
#pragma unroll
    for (int r = 0; r < 4; ++r) {
        float4 v0 = make_float4(acc[r][0], acc[r][1], acc[r][2], acc[r][3]);
        float4 v1 = make_float4(acc[r][4], acc[r][5], acc[r][6], acc[r][7]);
        float4* dst = (float4*)(h + (row0 + rbase + r) * COUT + cbase);
        dst[0] = v0; dst[1] = v1;
#pragma unroll
        for (int j = 0; j < 8; ++j) {
            psum[j] += acc[r][j];
            psq[j]  += acc[r][j] * acc[r][j];
        }
    }
#pragma unroll
    for (int j = 0; j < 8; ++j) {
        atomicAdd(&redsum[cbase + j], psum[j]);
        atomicAdd(&redsq[cbase + j], psq[j]);
    }
    __syncthreads();
    if (tid < COUT) {
        partials[(size_t)blockIdx.x * 256 + tid] = redsum[tid];
        partials[(size_t)blockIdx.x * 256 + COUT + tid] = redsq[tid];
    }
}

// ---------------------------------------------------------------------------
// 5) BN finalize: deterministic reduction of 2048 block partials -> scale/shift
// ---------------------------------------------------------------------------
__global__ void bn_finalize_kernel(const float* __restrict__ partials,
                                   const float* __restrict__ gamma,
                                   const float* __restrict__ beta,
                                   float* __restrict__ stats) {
    int c = threadIdx.x;   // 0..127
    float s = 0.f, sq = 0.f;
    for (int blk = 0; blk < 2048; ++blk) {
        s  += partials[(size_t)blk * 256 + c];
        sq += partials[(size_t)blk * 256 + COUT + c];
    }
    const float invn = 1.0f / (float)(B_ * N_);
    float mean = s * invn;
    float var  = sq * invn - mean * mean;
    float scale = gamma[c] / sqrtf(var + BN_EPS);
    float shift = beta[c] - mean * scale;
    stats[c] = scale;
    stats[COUT + c] = shift;
}

// ---------------------------------------------------------------------------
// 6) Gather K neighbors, fused BN affine + ReLU, max-pool over K.
//    Block = 2 queries x 128 channels; h rows are coalesced 512B reads.
// ---------------------------------------------------------------------------
__global__ __launch_bounds__(256) void gather_max_kernel(const float* __restrict__ h,
                                                         const int* __restrict__ knn_idx,
                                                         const float* __restrict__ stats,
                                                         float* __restrict__ out) {
    const int tid = threadIdx.x;
    const int c = tid & 127;
    const int qq = blockIdx.x * 2 + (tid >> 7);  // global query [0, 16*2048)
    const int b = qq >> 11;
    const int* idx = knn_idx + (size_t)qq * K_;
    const float scale = stats[c], shift = stats[COUT + c];
    const float* hb = h + (size_t)b * N_ * COUT;
    float m = -3.4e38f;
#pragma unroll
    for (int k = 0; k < K_; ++k) {
        float v = hb[(size_t)idx[k] * COUT + c];
        v = fmaf(v, scale, shift);
        v = fmaxf(v, 0.f);
        m = fmaxf(m, v);
    }
    out[B_ * NPOINT * 3 + (size_t)qq * COUT + c] = m;
}

// ---------------------------------------------------------------------------
extern "C" void kernel_launch(void* const* d_in, const int* in_sizes, int n_in,
                              void* d_out, int out_size, void* d_ws, size_t ws_size,
                              hipStream_t stream) {
    const float* xyz   = (const float*)d_in[0];  // [16,8192,3]
    const float* feat  = (const float*)d_in[1];  // [16,8192,64]
    const float* W     = (const float*)d_in[2];  // [128,64]
    const float* bias  = (const float*)d_in[3];  // [128]
    const float* gamma = (const float*)d_in[4];  // [128]
    const float* beta  = (const float*)d_in[5];  // [128]
    float* out = (float*)d_out;

    // workspace carving (all 256B-aligned by construction)
    char* ws = (char*)d_ws;
    int*   fps_idx  = (int*)(ws);                          // 16*2048*4        = 131072 B
    int*   knn_idx  = (int*)(ws + 131072);                 // 16*2048*16*4     = 2097152 B
    float* partials = (float*)(ws + 131072 + 2097152);     // 2048*256*4       = 2097152 B
    float* stats    = (float*)(ws + 131072 + 2097152 + 2097152);        // 256*4 = 1024 B
    float* h        = (float*)(ws + 131072 + 2097152 + 2097152 + 1024); // 16*8192*128*4 = 64 MiB

    // GEMM first is irrelevant (single stream serializes); dependency order:
    fps_kernel<<<B_, 1024, 0, stream>>>(xyz, fps_idx);
    newxyz_kernel<<<(B_ * NPOINT * 3 + 255) / 256, 256, 0, stream>>>(xyz, fps_idx, out);
    knn_kernel<<<dim3(NPOINT / 256, B_), 256, 0, stream>>>(xyz, fps_idx, knn_idx);
    gemm_kernel<<<(B_ * N_) / 64, 256, 0, stream>>>(feat, W, bias, h, partials);
    bn_finalize_kernel<<<1, COUT, 0, stream>>>(partials, gamma, beta, stats);
    gather_max_kernel<<<(B_ * NPOINT) / 2, 256, 0, stream>>>(h, knn_idx, stats, out);
}

// Round 2
// 4657.075 us; speedup vs baseline: 1.5497x; 1.5497x over previous
//
#include <hip/hip_runtime.h>
#include <hip/hip_bf16.h>

// Problem constants (from reference)
#define B_    16
#define N_    8192
#define NPOINT 2048
#define K_    16
#define CIN   64
#define COUT  128
#define BN_EPS 1e-5f

// ---------------------------------------------------------------------------
// DPP wave64 argmax step: bv/bi <- argmax vs lanes shifted by dpp ctrl.
// bound_ctrl=false keeps own value for lanes with no source (no-op for max).
// ---------------------------------------------------------------------------
template <int CTRL>
__device__ __forceinline__ void argmax_step(float& bv, int& bi) {
    int vb = __builtin_amdgcn_update_dpp(__builtin_bit_cast(int, bv),
                                         __builtin_bit_cast(int, bv),
                                         CTRL, 0xf, 0xf, false);
    int oi = __builtin_amdgcn_update_dpp(bi, bi, CTRL, 0xf, 0xf, false);
    float ov = __builtin_bit_cast(float, vb);
    bool take = (ov > bv) || (ov == bv && oi < bi);
    bv = take ? ov : bv;
    bi = take ? oi : bi;
}

// ---------------------------------------------------------------------------
// 1) Farthest point sampling: 1 block (256 thr, 4 waves) per batch.
//    All 8192 points in LDS (96 KiB) for direct centroid broadcast reads;
//    per-thread 32 points + distances in registers. One barrier/iteration
//    (double-buffered wave partials). Bit-exact numpy arithmetic:
//    ((dx*dx+dy*dy)+dz*dz) via _rn intrinsics, fminf, strict-> argmax with
//    min-index tie-break.
// ---------------------------------------------------------------------------
__global__ __launch_bounds__(256, 1) void fps_kernel(const float* __restrict__ xyz,
                                                     int* __restrict__ fps_idx) {
    const int b = blockIdx.x;
    const int t = threadIdx.x;
    const float* P = xyz + (size_t)b * N_ * 3;

    __shared__ float sxyz[N_ * 3];       // 96 KiB
    __shared__ float s_v[2][4];
    __shared__ int   s_i[2][4];

    for (int j = t; j < N_ * 3; j += 256) sxyz[j] = P[j];
    __syncthreads();

    float px[32], py[32], pz[32], dist[32];
#pragma unroll
    for (int k = 0; k < 32; ++k) {
        int gi = t + (k << 8);
        px[k] = sxyz[gi * 3 + 0];
        py[k] = sxyz[gi * 3 + 1];
        pz[k] = sxyz[gi * 3 + 2];
        dist[k] = 1e10f;
    }

    if (t == 0) fps_idx[b * NPOINT] = 0;

    int cur = 0;      // current farthest (centroid) index, uniform across block
    int buf = 0;
    const int wv_id = t >> 6;

    for (int it = 1; it < NPOINT; ++it) {
        // centroid: broadcast LDS read (all lanes same address)
        float cx = sxyz[cur * 3 + 0];
        float cy = sxyz[cur * 3 + 1];
        float cz = sxyz[cur * 3 + 2];

        float bv = -1.0f; int bi = 0;
#pragma unroll
        for (int k = 0; k < 32; ++k) {
            float dx = __fsub_rn(px[k], cx);
            float dy = __fsub_rn(py[k], cy);
            float dz = __fsub_rn(pz[k], cz);
            float d  = __fadd_rn(__fadd_rn(__fmul_rn(dx, dx), __fmul_rn(dy, dy)),
                                 __fmul_rn(dz, dz));
            float nd = fminf(dist[k], d);
            dist[k] = nd;
            // ascending k => ascending global index; strict > keeps lowest idx
            if (nd > bv) { bv = nd; bi = t + (k << 8); }
        }

        // wave64 argmax via DPP (result lands in lane 63)
        argmax_step<0x111>(bv, bi);   // row_shr:1
        argmax_step<0x112>(bv, bi);   // row_shr:2
        argmax_step<0x114>(bv, bi);   // row_shr:4
        argmax_step<0x118>(bv, bi);   // row_shr:8
        argmax_step<0x142>(bv, bi);   // row_bcast:15
        argmax_step<0x143>(bv, bi);   // row_bcast:31

        if ((t & 63) == 63) { s_v[buf][wv_id] = bv; s_i[buf][wv_id] = bi; }
        __syncthreads();

        // every thread combines the 4 wave partials (identical result)
        float wv = s_v[buf][0]; int wi = s_i[buf][0];
#pragma unroll
        for (int w = 1; w < 4; ++w) {
            float v2 = s_v[buf][w]; int i2 = s_i[buf][w];
            if (v2 > wv || (v2 == wv && i2 < wi)) { wv = v2; wi = i2; }
        }
        cur = wi;
        if (t == 0) fps_idx[b * NPOINT + it] = wi;
        buf ^= 1;
    }
}

// ---------------------------------------------------------------------------
// 2) new_xyz gather: out[b][q][c] = xyz[b][fps_idx[b][q]][c]
// ---------------------------------------------------------------------------
__global__ void newxyz_kernel(const float* __restrict__ xyz,
                              const int* __restrict__ fps_idx,
                              float* __restrict__ out) {
    int i = blockIdx.x * blockDim.x + threadIdx.x;
    if (i >= B_ * NPOINT * 3) return;
    int c = i % 3;
    int q = (i / 3) % NPOINT;
    int b = i / (3 * NPOINT);
    out[i] = xyz[((size_t)b * N_ + fps_idx[b * NPOINT + q]) * 3 + c];
}

// ---------------------------------------------------------------------------
// 3) kNN: thread per query, xyz tiled through LDS (broadcast reads),
//    16-deep sorted register list, strict < (stable / first-index ties).
// ---------------------------------------------------------------------------
#define KNN_TILE 1024
__global__ __launch_bounds__(256) void knn_kernel(const float* __restrict__ xyz,
                                                  const int* __restrict__ fps_idx,
                                                  int* __restrict__ knn_idx) {
    const int b = blockIdx.y;
    const int q = blockIdx.x * 256 + threadIdx.x;   // 0..2047
    const float* P = xyz + (size_t)b * N_ * 3;
    const int qi = fps_idx[b * NPOINT + q];
    const float qx = P[qi * 3 + 0], qy = P[qi * 3 + 1], qz = P[qi * 3 + 2];

    float bd[K_]; int bix[K_];
#pragma unroll
    for (int j = 0; j < K_; ++j) { bd[j] = 3.4e38f; bix[j] = 0; }

    __shared__ float sx[KNN_TILE], sy[KNN_TILE], sz[KNN_TILE];

    for (int tile = 0; tile < N_; tile += KNN_TILE) {
        for (int i = threadIdx.x; i < KNN_TILE; i += 256) {
            sx[i] = P[(tile + i) * 3 + 0];
            sy[i] = P[(tile + i) * 3 + 1];
            sz[i] = P[(tile + i) * 3 + 2];
        }
        __syncthreads();
        for (int i = 0; i < KNN_TILE; ++i) {
            float dx = __fsub_rn(qx, sx[i]);
            float dy = __fsub_rn(qy, sy[i]);
            float dz = __fsub_rn(qz, sz[i]);
            float d  = __fadd_rn(__fadd_rn(__fmul_rn(dx, dx), __fmul_rn(dy, dy)),
                                 __fmul_rn(dz, dz));
            if (d < bd[K_ - 1]) {              // strict: equal distances keep earlier idx
                bd[K_ - 1] = d; bix[K_ - 1] = tile + i;
#pragma unroll
                for (int j = K_ - 1; j > 0; --j) {
                    if (bd[j] < bd[j - 1]) {
                        float tv = bd[j]; bd[j] = bd[j - 1]; bd[j - 1] = tv;
                        int   ti = bix[j]; bix[j] = bix[j - 1]; bix[j - 1] = ti;
                    }
                }
            }
        }
        __syncthreads();
    }
#pragma unroll
    for (int j = 0; j < K_; ++j)
        knn_idx[((size_t)b * NPOINT + q) * K_ + j] = bix[j];
}

// ---------------------------------------------------------------------------
// 4) 1x1 conv GEMM: h[131072,128] = feat[131072,64] @ W^T + b, fp32 vector.
//    Block = 64 rows x 128 cols tile. Also emits per-block channel sum/sumsq.
// ---------------------------------------------------------------------------
__global__ __launch_bounds__(256) void gemm_kernel(const float* __restrict__ feat,
                                                   const float* __restrict__ W,
                                                   const float* __restrict__ bias,
                                                   float* __restrict__ h,
                                                   float* __restrict__ partials) {
    __shared__ float wT[64 * 132];      // wT[c*132 + o]
    __shared__ float fT[64 * 68];       // fT[c*68 + r]
    __shared__ float redsum[COUT], redsq[COUT];
    const int tid = threadIdx.x;
    const size_t row0 = (size_t)blockIdx.x * 64;

    for (int g = tid; g < COUT * CIN; g += 256) {
        int o = g >> 6, c = g & 63;
        wT[c * 132 + o] = W[g];
    }
    for (int g = tid; g < 64 * CIN; g += 256) {
        int r = g >> 6, c = g & 63;
        fT[c * 68 + r] = feat[(row0 + r) * CIN + c];
    }
    if (tid < COUT) { redsum[tid] = 0.f; redsq[tid] = 0.f; }
    __syncthreads();

    const int rbase = (tid >> 4) * 4;   // 0..60
    const int cbase = (tid & 15) * 8;   // 0..120

    float acc[4][8];
#pragma unroll
    for (int r = 0; r < 4; ++r)
#pragma unroll
        for (int j = 0; j < 8; ++j) acc[r][j] = bias[cbase + j];

    for (int c = 0; c < CIN; ++c) {
        float f0 = fT[c * 68 + rbase + 0];
        float f1 = fT[c * 68 + rbase + 1];
        float f2 = fT[c * 68 + rbase + 2];
        float f3 = fT[c * 68 + rbase + 3];
        float wv[8];
#pragma unroll
        for (int j = 0; j < 8; ++j) wv[j] = wT[c * 132 + cbase + j];
#pragma unroll
        for (int j = 0; j < 8; ++j) {
            acc[0][j] = fmaf(f0, wv[j], acc[0][j]);
            acc[1][j] = fmaf(f1, wv[j], acc[1][j]);
            acc[2][j] = fmaf(f2, wv[j], acc[2][j]);
            acc[3][j] = fmaf(f3, wv[j], acc[3][j]);
        }
    }

    float psum[8], psq[8];
#pragma unroll
    for (int j = 0; j < 8; ++j) { psum[j] = 0.f; psq[j] = 0.f; }
#pragma unroll
    for (int r = 0; r < 4; ++r) {
        float4 v0 = make_float4(acc[r][0], acc[r][1], acc[r][2], acc[r][3]);
        float4 v1 = make_float4(acc[r][4], acc[r][5], acc[r][6], acc[r][7]);
        float4* dst = (float4*)(h + (row0 + rbase + r) * COUT + cbase);
        dst[0] = v0; dst[1] = v1;
#pragma unroll
        for (int j = 0; j < 8; ++j) {
            psum[j] += acc[r][j];
            psq[j]  += acc[r][j] * acc[r][j];
        }
    }
#pragma unroll
    for (int j = 0; j < 8; ++j) {
        atomicAdd(&redsum[cbase + j], psum[j]);
        atomicAdd(&redsq[cbase + j], psq[j]);
    }
    __syncthreads();
    if (tid < COUT) {
        partials[(size_t)blockIdx.x * 256 + tid] = redsum[tid];
        partials[(size_t)blockIdx.x * 256 + COUT + tid] = redsq[tid];
    }
}

// ---------------------------------------------------------------------------
// 5) BN finalize: deterministic reduction of 2048 block partials -> scale/shift
// ---------------------------------------------------------------------------
__global__ void bn_finalize_kernel(const float* __restrict__ partials,
                                   const float* __restrict__ gamma,
                                   const float* __restrict__ beta,
                                   float* __restrict__ stats) {
    int c = threadIdx.x;   // 0..127
    float s = 0.f, sq = 0.f;
    for (int blk = 0; blk < 2048; ++blk) {
        s  += partials[(size_t)blk * 256 + c];
        sq += partials[(size_t)blk * 256 + COUT + c];
    }
    const float invn = 1.0f / (float)(B_ * N_);
    float mean = s * invn;
    float var  = sq * invn - mean * mean;
    float scale = gamma[c] / sqrtf(var + BN_EPS);
    float shift = beta[c] - mean * scale;
    stats[c] = scale;
    stats[COUT + c] = shift;
}

// ---------------------------------------------------------------------------
// 6) Gather K neighbors, fused BN affine + ReLU, max-pool over K.
//    Block = 8 queries x 32 lanes, float4 per lane (16B/lane coalesced).
// ---------------------------------------------------------------------------
__global__ __launch_bounds__(256) void gather_max_kernel(const float* __restrict__ h,
                                                         const int* __restrict__ knn_idx,
                                                         const float* __restrict__ stats,
                                                         float* __restrict__ out) {
    const int lane = threadIdx.x & 31;
    const int qq = blockIdx.x * 8 + (threadIdx.x >> 5);  // global query [0, 32768)
    const int b = qq >> 11;
    const int c4 = lane * 4;
    const int* idx = knn_idx + (size_t)qq * K_;
    const float4 scale = *(const float4*)(stats + c4);
    const float4 shift = *(const float4*)(stats + COUT + c4);
    const float* hb = h + (size_t)b * N_ * COUT;
    float4 m = make_float4(-3.4e38f, -3.4e38f, -3.4e38f, -3.4e38f);
#pragma unroll
    for (int k = 0; k < K_; ++k) {
        const float4 v = *(const float4*)(hb + (size_t)idx[k] * COUT + c4);
        m.x = fmaxf(m.x, fmaxf(fmaf(v.x, scale.x, shift.x), 0.f));
        m.y = fmaxf(m.y, fmaxf(fmaf(v.y, scale.y, shift.y), 0.f));
        m.z = fmaxf(m.z, fmaxf(fmaf(v.z, scale.z, shift.z), 0.f));
        m.w = fmaxf(m.w, fmaxf(fmaf(v.w, scale.w, shift.w), 0.f));
    }
    *(float4*)(out + B_ * NPOINT * 3 + (size_t)qq * COUT + c4) = m;
}

// ---------------------------------------------------------------------------
extern "C" void kernel_launch(void* const* d_in, const int* in_sizes, int n_in,
                              void* d_out, int out_size, void* d_ws, size_t ws_size,
                              hipStream_t stream) {
    const float* xyz   = (const float*)d_in[0];  // [16,8192,3]
    const float* feat  = (const float*)d_in[1];  // [16,8192,64]
    const float* W     = (const float*)d_in[2];  // [128,64]
    const float* bias  = (const float*)d_in[3];  // [128]
    const float* gamma = (const float*)d_in[4];  // [128]
    const float* beta  = (const float*)d_in[5];  // [128]
    float* out = (float*)d_out;

    // workspace carving (all 256B-aligned by construction)
    char* ws = (char*)d_ws;
    int*   fps_idx  = (int*)(ws);                          // 16*2048*4        = 131072 B
    int*   knn_idx  = (int*)(ws + 131072);                 // 16*2048*16*4     = 2097152 B
    float* partials = (float*)(ws + 131072 + 2097152);     // 2048*256*4       = 2097152 B
    float* stats    = (float*)(ws + 131072 + 2097152 + 2097152);        // 256*4 = 1024 B
    float* h        = (float*)(ws + 131072 + 2097152 + 2097152 + 1024); // 16*8192*128*4 = 64 MiB

    fps_kernel<<<B_, 256, 0, stream>>>(xyz, fps_idx);
    newxyz_kernel<<<(B_ * NPOINT * 3 + 255) / 256, 256, 0, stream>>>(xyz, fps_idx, out);
    knn_kernel<<<dim3(NPOINT / 256, B_), 256, 0, stream>>>(xyz, fps_idx, knn_idx);
    gemm_kernel<<<(B_ * N_) / 64, 256, 0, stream>>>(feat, W, bias, h, partials);
    bn_finalize_kernel<<<1, COUT, 0, stream>>>(partials, gamma, beta, stats);
    gather_max_kernel<<<(B_ * NPOINT) / 8, 256, 0, stream>>>(h, knn_idx, stats, out);
}